// Round 4
// baseline (137.754 us; speedup 1.0000x reference)
//
#include <hip/hip_runtime.h>
#include <hip/hip_bf16.h>

#define T_ 64
#define S_ 64
#define B_ 128
#define E_ 64
#define H_ 4

typedef float f32x4 __attribute__((ext_vector_type(4)));
typedef short bf16x8 __attribute__((ext_vector_type(8)));

static __device__ __forceinline__ short f2b(float f) {
    union { __hip_bfloat16 h; short s; } u;
    u.h = __float2bfloat16(f);
    return u.s;
}

// ---------------------------------------------------------------------------
// K1: qkv projection (unchanged). qkv layout: [3][T][B][E]
// ---------------------------------------------------------------------------
__global__ __launch_bounds__(256) void k_qkv(
    const float* __restrict__ qin, const float* __restrict__ kin,
    const float* __restrict__ vin, const float* __restrict__ W,
    const float* __restrict__ bias, float* __restrict__ qkv)
{
    __shared__ float xs[3][32 * 68];
    __shared__ float WTs[64 * 68];
    const int tid = threadIdx.x;
    const int row0 = blockIdx.x * 32;

    #pragma unroll
    for (int l = 0; l < 6; ++l) {
        int f4 = l * 256 + tid;
        int src = f4 >> 9, rem = f4 & 511;
        int r = rem >> 4, e0 = (rem & 15) << 2;
        const float* xin = (src == 0) ? qin : (src == 1 ? kin : vin);
        float4 xv = reinterpret_cast<const float4*>(xin)[(size_t)(row0 + r) * 16 + (e0 >> 2)];
        float* dst = &xs[src][r * 68];
        dst[e0] = xv.x; dst[e0 + 1] = xv.y; dst[e0 + 2] = xv.z; dst[e0 + 3] = xv.w;
    }

    const int rq = tid >> 5, og = tid & 31;
    const int r0 = rq * 4, op0 = og * 2;

    for (int seg = 0; seg < 3; ++seg) {
        __syncthreads();
        #pragma unroll
        for (int l = 0; l < 4; ++l) {
            int f4 = l * 256 + tid;
            int o = f4 >> 4, e0 = (f4 & 15) << 2;
            float4 wv = reinterpret_cast<const float4*>(W)[(size_t)(seg * 64 + o) * 16 + (e0 >> 2)];
            WTs[(e0 + 0) * 68 + o] = wv.x; WTs[(e0 + 1) * 68 + o] = wv.y;
            WTs[(e0 + 2) * 68 + o] = wv.z; WTs[(e0 + 3) * 68 + o] = wv.w;
        }
        __syncthreads();

        float acc[4][2];
        #pragma unroll
        for (int rr = 0; rr < 4; ++rr) {
            acc[rr][0] = bias[seg * 64 + op0];
            acc[rr][1] = bias[seg * 64 + op0 + 1];
        }
        const float* xsrc = xs[seg];
        #pragma unroll 4
        for (int e = 0; e < 64; ++e) {
            float w0 = WTs[e * 68 + op0];
            float w1 = WTs[e * 68 + op0 + 1];
            #pragma unroll
            for (int rr = 0; rr < 4; ++rr) {
                float xv = xsrc[(r0 + rr) * 68 + e];
                acc[rr][0] += xv * w0;
                acc[rr][1] += xv * w1;
            }
        }
        #pragma unroll
        for (int rr = 0; rr < 4; ++rr) {
            float2 ov = make_float2(acc[rr][0], acc[rr][1]);
            reinterpret_cast<float2*>(
                &qkv[((size_t)seg * T_ * B_ + row0 + r0 + rr) * E_ + op0])[0] = ov;
        }
    }
}

// ---------------------------------------------------------------------------
// K2a: fused relation-projection + logits (MFMA, register-direct A).
// grid = 64 i * 8 jq = 512 wgs, 512 thr = 8 waves, 2 wg/CU (16 waves).
// Wave w owns b-tile w (16 b) for 8 j's. Per j: A fragments loaded straight
// from global to VGPRs (lane (c,rq): row w*16+c, k = ks*32+rq*8..+7 -> 4
// contiguous float4 loads), cvt fp32->bf16 in regs, 16 MFMA vs B (relW bf16,
// fragment-linear in 16 KB LDS). Manual 1-deep pipeline: cvt current j,
// issue j+1 A loads + j kvv loads, MFMA, epilogue. No inline waitcnt, no
// barriers in the loop. Logits buffered in regs, flushed coalesced.
// ---------------------------------------------------------------------------
__global__ __launch_bounds__(512, 4) void k_logits_mfma(
    const float* __restrict__ rel, const float* __restrict__ relW,
    const float* __restrict__ relBias, const float* __restrict__ qkv,
    float* __restrict__ logits)
{
    __shared__ char Bs[16384];           // bf16 W, fragment-linear (16 KB)

    const int tid = threadIdx.x;
    const int w   = tid >> 6;
    const int l   = tid & 63;
    const int c   = l & 15;      // MFMA col lane
    const int rq  = l >> 4;      // MFMA row-quadrant / k-subchunk
    const int i   = blockIdx.x >> 3;
    const int jb  = (blockIdx.x & 7) * 8;

    // ---- stage relW -> Bs (bf16, fragment-linear) ----
    #pragma unroll
    for (int li = 0; li < 4; ++li) {
        int f4 = li * 512 + tid;             // 0..2047 = o*16 + e4
        int o = f4 >> 4, e4 = f4 & 15;
        float4 wv = reinterpret_cast<const float4*>(relW)[f4];
        ushort4 bv;
        bv.x = (ushort)f2b(wv.x); bv.y = (ushort)f2b(wv.y);
        bv.z = (ushort)f2b(wv.z); bv.w = (ushort)f2b(wv.w);
        int ot = o >> 4, cc = o & 15;
        int ks = e4 >> 3, rqb = (e4 & 7) >> 1, half = e4 & 1;
        int dest = (ot * 2 + ks) * 1024 + (rqb * 16 + cc) * 16 + half * 8;
        *reinterpret_cast<ushort4*>(Bs + dest) = bv;
    }

    // ---- hoist q + rel biases into registers ----
    float qpre[4][4], bbv[4];
    {
        const float* qrow = qkv + (size_t)i * (B_ * E_);
        #pragma unroll
        for (int h = 0; h < 4; ++h) {
            float ba = relBias[h * 16 + c];
            bbv[h] = relBias[64 + h * 16 + c];
            #pragma unroll
            for (int r = 0; r < 4; ++r) {
                int b = w * 16 + rq * 4 + r;
                qpre[h][r] = qrow[b * E_ + h * 16 + c] + ba;
            }
        }
    }
    __syncthreads();   // Bs ready

    // per-lane A offset (floats): row (w*16+c), k-base rq*8
    const int arow = ((w * 16 + c) * E_) + rq * 8;
    const int kbase = (w * 16 + rq * 4) * E_;

    float lbuf[8];
    float4 a0, a1, a2, a3;
    {
        const float* ab = rel + ((size_t)jb * S_ + i) * (size_t)(B_ * E_) + arow;
        a0 = *(const float4*)(ab);          // ks=0, k 0..3  (of rq's 8)
        a1 = *(const float4*)(ab + 4);      // ks=0, k 4..7
        a2 = *(const float4*)(ab + 32);     // ks=1
        a3 = *(const float4*)(ab + 36);
    }

    #pragma unroll 1
    for (int t = 0; t < 8; ++t) {
        const int j = jb + t;

        // convert current j's A to bf16 fragments (frees a0..a3)
        bf16x8 af[2];
        {
            bf16x8 a;
            a[0] = f2b(a0.x); a[1] = f2b(a0.y); a[2] = f2b(a0.z); a[3] = f2b(a0.w);
            a[4] = f2b(a1.x); a[5] = f2b(a1.y); a[6] = f2b(a1.z); a[7] = f2b(a1.w);
            af[0] = a;
            a[0] = f2b(a2.x); a[1] = f2b(a2.y); a[2] = f2b(a2.z); a[3] = f2b(a2.w);
            a[4] = f2b(a3.x); a[5] = f2b(a3.y); a[6] = f2b(a3.z); a[7] = f2b(a3.w);
            af[1] = a;
        }

        // prefetch next j's A (full iteration of latency slack)
        if (t < 7) {
            const float* ab = rel + ((size_t)(j + 1) * S_ + i) * (size_t)(B_ * E_) + arow;
            a0 = *(const float4*)(ab);
            a1 = *(const float4*)(ab + 4);
            a2 = *(const float4*)(ab + 32);
            a3 = *(const float4*)(ab + 36);
        }

        // k-values for this j's epilogue (L2-hot; hidden under MFMA)
        float kvv[4][4];
        {
            const float* krow = qkv + ((size_t)(T_ * B_) + (size_t)j * B_) * E_ + kbase;
            #pragma unroll
            for (int h = 0; h < 4; ++h)
                #pragma unroll
                for (int r = 0; r < 4; ++r)
                    kvv[h][r] = krow[r * E_ + h * 16 + c];
        }

        // GEMM: 8 o-tiles x 2 k-steps; B reads lane-linear (conflict-free)
        f32x4 acc[8];
        #pragma unroll
        for (int ot = 0; ot < 8; ++ot) acc[ot] = (f32x4){0.f, 0.f, 0.f, 0.f};
        #pragma unroll
        for (int ot = 0; ot < 8; ++ot) {
            #pragma unroll
            for (int ks = 0; ks < 2; ++ks) {
                bf16x8 bfr = *(const bf16x8*)(Bs + (ot * 2 + ks) * 1024 + l * 16);
                acc[ot] = __builtin_amdgcn_mfma_f32_16x16x32_bf16(af[ks], bfr, acc[ot], 0, 0, 0);
            }
        }

        // epilogue: v[idx=h*4+r] per lane; butterfly reduce-scatter over c-lanes
        float v[16];
        #pragma unroll
        for (int h = 0; h < 4; ++h)
            #pragma unroll
            for (int r = 0; r < 4; ++r)
                v[h * 4 + r] = (qpre[h][r] + acc[h][r]) *
                               (kvv[h][r] + bbv[h] + acc[4 + h][r]);
        #pragma unroll
        for (int k = 0; k < 8; ++k) {
            float x = (c & 1) ? v[2 * k + 1] : v[2 * k];
            float y = (c & 1) ? v[2 * k] : v[2 * k + 1];
            v[k] = x + __shfl_xor(y, 1);
        }
        #pragma unroll
        for (int k = 0; k < 4; ++k) {
            float x = (c & 2) ? v[2 * k + 1] : v[2 * k];
            float y = (c & 2) ? v[2 * k] : v[2 * k + 1];
            v[k] = x + __shfl_xor(y, 2);
        }
        #pragma unroll
        for (int k = 0; k < 2; ++k) {
            float x = (c & 4) ? v[2 * k + 1] : v[2 * k];
            float y = (c & 4) ? v[2 * k] : v[2 * k + 1];
            v[k] = x + __shfl_xor(y, 4);
        }
        {
            float x = (c & 8) ? v[1] : v[0];
            float y = (c & 8) ? v[0] : v[1];
            lbuf[t] = (x + __shfl_xor(y, 8)) * 0.0625f;
        }
    }

    // flush: lane (w,rq,c) owns logits[i][b = w*16+rq*4+(c&3)][h = c>>2][jb..jb+7]
    {
        const int hh = c >> 2, rr = c & 3;
        const int b = w * 16 + rq * 4 + rr;
        float* dst = &logits[(((size_t)i * B_ + b) * H_ + hh) * S_ + jb];
        *reinterpret_cast<float4*>(dst) = make_float4(lbuf[0], lbuf[1], lbuf[2], lbuf[3]);
        *reinterpret_cast<float4*>(dst + 4) = make_float4(lbuf[4], lbuf[5], lbuf[6], lbuf[7]);
    }
}

// ---------------------------------------------------------------------------
// K2b: softmax over j + PV + out-projection (unchanged).
// ---------------------------------------------------------------------------
__global__ __launch_bounds__(256) void k_attn(
    const float* __restrict__ logits, const float* __restrict__ qkv,
    const float* __restrict__ Wout, const float* __restrict__ bout,
    float* __restrict__ out)
{
    __shared__ float wsm[4][H_][S_];
    __shared__ float ap[4][68];
    const int tid = threadIdx.x;
    const int i = blockIdx.x >> 5;
    const int bq = blockIdx.x & 31;
    const int w = tid >> 6, l = tid & 63;
    const int b = bq * 4 + w;

    const float* lg = logits + ((size_t)i * B_ + b) * H_ * S_;
    const int h = l >> 4, sub = l & 15;
    float v0 = lg[h * S_ + sub];
    float v1 = lg[h * S_ + sub + 16];
    float v2 = lg[h * S_ + sub + 32];
    float v3 = lg[h * S_ + sub + 48];
    float m = fmaxf(fmaxf(v0, v1), fmaxf(v2, v3));
    #pragma unroll
    for (int d = 1; d < 16; d <<= 1) m = fmaxf(m, __shfl_xor(m, d));
    float e0 = expf(v0 - m), e1 = expf(v1 - m), e2 = expf(v2 - m), e3 = expf(v3 - m);
    float ss = e0 + e1 + e2 + e3;
    #pragma unroll
    for (int d = 1; d < 16; d <<= 1) ss += __shfl_xor(ss, d);
    float inv = 1.0f / ss;
    wsm[w][h][sub] = e0 * inv;
    wsm[w][h][sub + 16] = e1 * inv;
    wsm[w][h][sub + 32] = e2 * inv;
    wsm[w][h][sub + 48] = e3 * inv;
    __syncthreads();

    const float* vbase = qkv + (size_t)2 * T_ * B_ * E_ + (size_t)b * E_;
    const float* wrow = &wsm[w][l >> 4][0];
    float acc = 0.f;
    #pragma unroll 4
    for (int j = 0; j < S_; ++j) acc += wrow[j] * vbase[(size_t)j * B_ * E_ + l];
    ap[w][l] = acc;
    __syncthreads();

    const float* wo = Wout + l * E_;
    const float* apw = ap[w];
    float oacc = bout[l];
    #pragma unroll 4
    for (int e = 0; e < E_; ++e) oacc += apw[e] * wo[e];
    out[((size_t)i * B_ + b) * E_ + l] = oacc;
}

// ---------------------------------------------------------------------------
extern "C" void kernel_launch(void* const* d_in, const int* in_sizes, int n_in,
                              void* d_out, int out_size, void* d_ws, size_t ws_size,
                              hipStream_t stream)
{
    const float* qin = (const float*)d_in[0];
    const float* kin = (const float*)d_in[1];
    const float* vin = (const float*)d_in[2];
    const float* rel = (const float*)d_in[3];
    const float* ipw = (const float*)d_in[4];
    const float* ipb = (const float*)d_in[5];
    const float* rw  = (const float*)d_in[6];
    const float* rb  = (const float*)d_in[7];
    const float* ow  = (const float*)d_in[8];
    const float* obias = (const float*)d_in[9];

    float* qkv = (float*)d_ws;                       // 3*64*128*64 fl = 6 MB
    float* logits = qkv + 3 * T_ * B_ * E_;          // 64*128*4*64 fl = 8 MB
    float* out = (float*)d_out;

    k_qkv<<<dim3(256), dim3(256), 0, stream>>>(qin, kin, vin, ipw, ipb, qkv);
    k_logits_mfma<<<dim3(512), dim3(512), 0, stream>>>(rel, rw, rb, qkv, logits);
    k_attn<<<dim3(2048), dim3(256), 0, stream>>>(logits, qkv, ow, obias, out);
}

// Round 5
// 68.990 us; speedup vs baseline: 1.9967x; 1.9967x over previous
//
#include <hip/hip_runtime.h>
#include <hip/hip_bf16.h>

#define T_ 64
#define S_ 64
#define B_ 128
#define E_ 64
#define H_ 4

typedef float f32x4 __attribute__((ext_vector_type(4)));
typedef short bf16x8 __attribute__((ext_vector_type(8)));

static __device__ __forceinline__ short f2b(float f) {
    union { __hip_bfloat16 h; short s; } u;
    u.h = __float2bfloat16(f);
    return u.s;
}

// ---------------------------------------------------------------------------
// K1: qkv projection (unchanged). qkv layout: [3][T][B][E]
// ---------------------------------------------------------------------------
__global__ __launch_bounds__(256) void k_qkv(
    const float* __restrict__ qin, const float* __restrict__ kin,
    const float* __restrict__ vin, const float* __restrict__ W,
    const float* __restrict__ bias, float* __restrict__ qkv)
{
    __shared__ float xs[3][32 * 68];
    __shared__ float WTs[64 * 68];
    const int tid = threadIdx.x;
    const int row0 = blockIdx.x * 32;

    #pragma unroll
    for (int l = 0; l < 6; ++l) {
        int f4 = l * 256 + tid;
        int src = f4 >> 9, rem = f4 & 511;
        int r = rem >> 4, e0 = (rem & 15) << 2;
        const float* xin = (src == 0) ? qin : (src == 1 ? kin : vin);
        float4 xv = reinterpret_cast<const float4*>(xin)[(size_t)(row0 + r) * 16 + (e0 >> 2)];
        float* dst = &xs[src][r * 68];
        dst[e0] = xv.x; dst[e0 + 1] = xv.y; dst[e0 + 2] = xv.z; dst[e0 + 3] = xv.w;
    }

    const int rq = tid >> 5, og = tid & 31;
    const int r0 = rq * 4, op0 = og * 2;

    for (int seg = 0; seg < 3; ++seg) {
        __syncthreads();
        #pragma unroll
        for (int l = 0; l < 4; ++l) {
            int f4 = l * 256 + tid;
            int o = f4 >> 4, e0 = (f4 & 15) << 2;
            float4 wv = reinterpret_cast<const float4*>(W)[(size_t)(seg * 64 + o) * 16 + (e0 >> 2)];
            WTs[(e0 + 0) * 68 + o] = wv.x; WTs[(e0 + 1) * 68 + o] = wv.y;
            WTs[(e0 + 2) * 68 + o] = wv.z; WTs[(e0 + 3) * 68 + o] = wv.w;
        }
        __syncthreads();

        float acc[4][2];
        #pragma unroll
        for (int rr = 0; rr < 4; ++rr) {
            acc[rr][0] = bias[seg * 64 + op0];
            acc[rr][1] = bias[seg * 64 + op0 + 1];
        }
        const float* xsrc = xs[seg];
        #pragma unroll 4
        for (int e = 0; e < 64; ++e) {
            float w0 = WTs[e * 68 + op0];
            float w1 = WTs[e * 68 + op0 + 1];
            #pragma unroll
            for (int rr = 0; rr < 4; ++rr) {
                float xv = xsrc[(r0 + rr) * 68 + e];
                acc[rr][0] += xv * w0;
                acc[rr][1] += xv * w1;
            }
        }
        #pragma unroll
        for (int rr = 0; rr < 4; ++rr) {
            float2 ov = make_float2(acc[rr][0], acc[rr][1]);
            reinterpret_cast<float2*>(
                &qkv[((size_t)seg * T_ * B_ + row0 + r0 + rr) * E_ + op0])[0] = ov;
        }
    }
}

// ---------------------------------------------------------------------------
// K2a: fused relation-projection + logits (MFMA, register-direct A).
// grid = 64 i * 8 jq = 512 wgs, 512 thr = 8 waves.
// __launch_bounds__(512, 2): 2 blocks/CU -> 16 waves/CU -> 128-VGPR cap.
// (NOT (512,4): hipcc treats arg2 as blocks/CU -> 64-VGPR cap -> spills;
//  round-4 post-mortem: FETCH 293MB of scratch traffic, 136us.)
// Wave w owns b-tile w (16 b) for 8 j's. Per j: A fragments loaded straight
// from global to VGPRs (lane (c,rq): row w*16+c, k = ks*32+rq*8..+7), cvt
// fp32->bf16 in regs, 16 MFMA vs B (relW bf16, fragment-linear, 16 KB LDS).
// 1-deep pipeline: cvt j, issue j+1 A loads + j kvv loads, MFMA, epilogue.
// No barriers/waitcnt in the loop. Logits buffered in regs, coalesced flush.
// ---------------------------------------------------------------------------
__global__ __launch_bounds__(512, 2) void k_logits_mfma(
    const float* __restrict__ rel, const float* __restrict__ relW,
    const float* __restrict__ relBias, const float* __restrict__ qkv,
    float* __restrict__ logits)
{
    __shared__ char Bs[16384];           // bf16 W, fragment-linear (16 KB)

    const int tid = threadIdx.x;
    const int w   = tid >> 6;
    const int l   = tid & 63;
    const int c   = l & 15;      // MFMA col lane
    const int rq  = l >> 4;      // MFMA row-quadrant / k-subchunk
    const int i   = blockIdx.x >> 3;
    const int jb  = (blockIdx.x & 7) * 8;

    // ---- stage relW -> Bs (bf16, fragment-linear) ----
    #pragma unroll
    for (int li = 0; li < 4; ++li) {
        int f4 = li * 512 + tid;             // 0..2047 = o*16 + e4
        int o = f4 >> 4, e4 = f4 & 15;
        float4 wv = reinterpret_cast<const float4*>(relW)[f4];
        ushort4 bv;
        bv.x = (ushort)f2b(wv.x); bv.y = (ushort)f2b(wv.y);
        bv.z = (ushort)f2b(wv.z); bv.w = (ushort)f2b(wv.w);
        int ot = o >> 4, cc = o & 15;
        int ks = e4 >> 3, rqb = (e4 & 7) >> 1, half = e4 & 1;
        int dest = (ot * 2 + ks) * 1024 + (rqb * 16 + cc) * 16 + half * 8;
        *reinterpret_cast<ushort4*>(Bs + dest) = bv;
    }

    // ---- hoist q + rel biases into registers ----
    float qpre[4][4], bbv[4];
    {
        const float* qrow = qkv + (size_t)i * (B_ * E_);
        #pragma unroll
        for (int h = 0; h < 4; ++h) {
            float ba = relBias[h * 16 + c];
            bbv[h] = relBias[64 + h * 16 + c];
            #pragma unroll
            for (int r = 0; r < 4; ++r) {
                int b = w * 16 + rq * 4 + r;
                qpre[h][r] = qrow[b * E_ + h * 16 + c] + ba;
            }
        }
    }
    __syncthreads();   // Bs ready

    // per-lane A offset (floats): row (w*16+c), k-base rq*8
    const int arow = ((w * 16 + c) * E_) + rq * 8;
    const int kbase = (w * 16 + rq * 4) * E_;

    float lbuf[8];
    float4 a0, a1, a2, a3;
    {
        const float* ab = rel + ((size_t)jb * S_ + i) * (size_t)(B_ * E_) + arow;
        a0 = *(const float4*)(ab);          // ks=0, k 0..3  (of rq's 8)
        a1 = *(const float4*)(ab + 4);      // ks=0, k 4..7
        a2 = *(const float4*)(ab + 32);     // ks=1
        a3 = *(const float4*)(ab + 36);
    }

    #pragma unroll 1
    for (int t = 0; t < 8; ++t) {
        const int j = jb + t;

        // convert current j's A to bf16 fragments (frees a0..a3)
        bf16x8 af[2];
        {
            bf16x8 a;
            a[0] = f2b(a0.x); a[1] = f2b(a0.y); a[2] = f2b(a0.z); a[3] = f2b(a0.w);
            a[4] = f2b(a1.x); a[5] = f2b(a1.y); a[6] = f2b(a1.z); a[7] = f2b(a1.w);
            af[0] = a;
            a[0] = f2b(a2.x); a[1] = f2b(a2.y); a[2] = f2b(a2.z); a[3] = f2b(a2.w);
            a[4] = f2b(a3.x); a[5] = f2b(a3.y); a[6] = f2b(a3.z); a[7] = f2b(a3.w);
            af[1] = a;
        }

        // prefetch next j's A (full iteration of latency slack)
        if (t < 7) {
            const float* ab = rel + ((size_t)(j + 1) * S_ + i) * (size_t)(B_ * E_) + arow;
            a0 = *(const float4*)(ab);
            a1 = *(const float4*)(ab + 4);
            a2 = *(const float4*)(ab + 32);
            a3 = *(const float4*)(ab + 36);
        }

        // k-values for this j's epilogue (L2-hot; hidden under MFMA)
        float kvv[4][4];
        {
            const float* krow = qkv + ((size_t)(T_ * B_) + (size_t)j * B_) * E_ + kbase;
            #pragma unroll
            for (int h = 0; h < 4; ++h)
                #pragma unroll
                for (int r = 0; r < 4; ++r)
                    kvv[h][r] = krow[r * E_ + h * 16 + c];
        }

        // GEMM: 8 o-tiles x 2 k-steps; B reads lane-linear (conflict-free)
        f32x4 acc[8];
        #pragma unroll
        for (int ot = 0; ot < 8; ++ot) acc[ot] = (f32x4){0.f, 0.f, 0.f, 0.f};
        #pragma unroll
        for (int ot = 0; ot < 8; ++ot) {
            #pragma unroll
            for (int ks = 0; ks < 2; ++ks) {
                bf16x8 bfr = *(const bf16x8*)(Bs + (ot * 2 + ks) * 1024 + l * 16);
                acc[ot] = __builtin_amdgcn_mfma_f32_16x16x32_bf16(af[ks], bfr, acc[ot], 0, 0, 0);
            }
        }

        // epilogue: v[idx=h*4+r] per lane; butterfly reduce-scatter over c-lanes
        float v[16];
        #pragma unroll
        for (int h = 0; h < 4; ++h)
            #pragma unroll
            for (int r = 0; r < 4; ++r)
                v[h * 4 + r] = (qpre[h][r] + acc[h][r]) *
                               (kvv[h][r] + bbv[h] + acc[4 + h][r]);
        #pragma unroll
        for (int k = 0; k < 8; ++k) {
            float x = (c & 1) ? v[2 * k + 1] : v[2 * k];
            float y = (c & 1) ? v[2 * k] : v[2 * k + 1];
            v[k] = x + __shfl_xor(y, 1);
        }
        #pragma unroll
        for (int k = 0; k < 4; ++k) {
            float x = (c & 2) ? v[2 * k + 1] : v[2 * k];
            float y = (c & 2) ? v[2 * k] : v[2 * k + 1];
            v[k] = x + __shfl_xor(y, 2);
        }
        #pragma unroll
        for (int k = 0; k < 2; ++k) {
            float x = (c & 4) ? v[2 * k + 1] : v[2 * k];
            float y = (c & 4) ? v[2 * k] : v[2 * k + 1];
            v[k] = x + __shfl_xor(y, 4);
        }
        {
            float x = (c & 8) ? v[1] : v[0];
            float y = (c & 8) ? v[0] : v[1];
            lbuf[t] = (x + __shfl_xor(y, 8)) * 0.0625f;
        }
    }

    // flush: lane (w,rq,c) owns logits[i][b = w*16+rq*4+(c&3)][h = c>>2][jb..jb+7]
    {
        const int hh = c >> 2, rr = c & 3;
        const int b = w * 16 + rq * 4 + rr;
        float* dst = &logits[(((size_t)i * B_ + b) * H_ + hh) * S_ + jb];
        *reinterpret_cast<float4*>(dst) = make_float4(lbuf[0], lbuf[1], lbuf[2], lbuf[3]);
        *reinterpret_cast<float4*>(dst + 4) = make_float4(lbuf[4], lbuf[5], lbuf[6], lbuf[7]);
    }
}

// ---------------------------------------------------------------------------
// K2b: softmax over j + PV + out-projection (unchanged).
// ---------------------------------------------------------------------------
__global__ __launch_bounds__(256) void k_attn(
    const float* __restrict__ logits, const float* __restrict__ qkv,
    const float* __restrict__ Wout, const float* __restrict__ bout,
    float* __restrict__ out)
{
    __shared__ float wsm[4][H_][S_];
    __shared__ float ap[4][68];
    const int tid = threadIdx.x;
    const int i = blockIdx.x >> 5;
    const int bq = blockIdx.x & 31;
    const int w = tid >> 6, l = tid & 63;
    const int b = bq * 4 + w;

    const float* lg = logits + ((size_t)i * B_ + b) * H_ * S_;
    const int h = l >> 4, sub = l & 15;
    float v0 = lg[h * S_ + sub];
    float v1 = lg[h * S_ + sub + 16];
    float v2 = lg[h * S_ + sub + 32];
    float v3 = lg[h * S_ + sub + 48];
    float m = fmaxf(fmaxf(v0, v1), fmaxf(v2, v3));
    #pragma unroll
    for (int d = 1; d < 16; d <<= 1) m = fmaxf(m, __shfl_xor(m, d));
    float e0 = expf(v0 - m), e1 = expf(v1 - m), e2 = expf(v2 - m), e3 = expf(v3 - m);
    float ss = e0 + e1 + e2 + e3;
    #pragma unroll
    for (int d = 1; d < 16; d <<= 1) ss += __shfl_xor(ss, d);
    float inv = 1.0f / ss;
    wsm[w][h][sub] = e0 * inv;
    wsm[w][h][sub + 16] = e1 * inv;
    wsm[w][h][sub + 32] = e2 * inv;
    wsm[w][h][sub + 48] = e3 * inv;
    __syncthreads();

    const float* vbase = qkv + (size_t)2 * T_ * B_ * E_ + (size_t)b * E_;
    const float* wrow = &wsm[w][l >> 4][0];
    float acc = 0.f;
    #pragma unroll 4
    for (int j = 0; j < S_; ++j) acc += wrow[j] * vbase[(size_t)j * B_ * E_ + l];
    ap[w][l] = acc;
    __syncthreads();

    const float* wo = Wout + l * E_;
    const float* apw = ap[w];
    float oacc = bout[l];
    #pragma unroll 4
    for (int e = 0; e < E_; ++e) oacc += apw[e] * wo[e];
    out[((size_t)i * B_ + b) * E_ + l] = oacc;
}

// ---------------------------------------------------------------------------
extern "C" void kernel_launch(void* const* d_in, const int* in_sizes, int n_in,
                              void* d_out, int out_size, void* d_ws, size_t ws_size,
                              hipStream_t stream)
{
    const float* qin = (const float*)d_in[0];
    const float* kin = (const float*)d_in[1];
    const float* vin = (const float*)d_in[2];
    const float* rel = (const float*)d_in[3];
    const float* ipw = (const float*)d_in[4];
    const float* ipb = (const float*)d_in[5];
    const float* rw  = (const float*)d_in[6];
    const float* rb  = (const float*)d_in[7];
    const float* ow  = (const float*)d_in[8];
    const float* obias = (const float*)d_in[9];

    float* qkv = (float*)d_ws;                       // 3*64*128*64 fl = 6 MB
    float* logits = qkv + 3 * T_ * B_ * E_;          // 64*128*4*64 fl = 8 MB
    float* out = (float*)d_out;

    k_qkv<<<dim3(256), dim3(256), 0, stream>>>(qin, kin, vin, ipw, ipb, qkv);
    k_logits_mfma<<<dim3(512), dim3(512), 0, stream>>>(rel, rw, rb, qkv, logits);
    k_attn<<<dim3(2048), dim3(256), 0, stream>>>(logits, qkv, ow, obias, out);
}